// Round 2
// baseline (119.429 us; speedup 1.0000x reference)
//
#include <hip/hip_runtime.h>

// x: [B=16, T=16384, C=64] fp32. bp_sos/lp_sos: [2,6] fp32 rows (b0,b1,b2,a0,a1,a2; a0==1).
#define B_LEN 16
#define T_LEN 16384
#define C_LEN 64
#define CHUNK 64    // output samples per thread; 2x compute amp (warm 64)
#define WARM  64    // zero-state warmup; transient ~0.83^64 ~ 7e-6 (empirically safe: absmax 0.0156)

// R7: R6's register pipeline never materialized (VGPR=28, dur flat): the backend
// scheduler sank the prefetch loads back to their uses. Two causes, two fixes:
//  1. __launch_bounds__(256, 4): grid gives exactly 4 waves/SIMD, so VGPR<=128 is
//     free. Without the min-waves arg the allocator targets ~64 VGPR and the
//     scheduler register-minimizes, collapsing the pipeline.
//  2. __builtin_amdgcn_sched_barrier(0) after each {consume 8; reload 8} phase:
//     bounds the scheduling regions so loads can't sink past the fence. The
//     waitcnt pass then emits counted vmcnt(~24-31) waits at first use -- only
//     the oldest 8 of 32 in-flight loads are waited on (AITER-style pipeline,
//     compiler-generated).
// Prefetch distance: each group is issued 3 phases (~24 samples, >1000 issue-cy)
// before consumption -> covers ~900cy HBM-miss latency.
// step() arithmetic order unchanged -> bit-identical output (absmax 0.015625).
__global__ __launch_bounds__(256, 4) void iir_pipe_kernel(
    const float* __restrict__ x,
    const float* __restrict__ bp,
    const float* __restrict__ lp,
    float* __restrict__ out)
{
    const int c     = threadIdx.x & 63;        // channel within batch
    const int bsub  = threadIdx.x >> 6;        // 0..3
    const int b     = blockIdx.y * 4 + bsub;   // batch 0..15
    const int chunk = blockIdx.x;              // 0..T/CHUNK-1

    // Uniform coefficients -> scalar (SGPR) loads. a's negated so updates are pure FMA.
    const float b10 = bp[0], b11 = bp[1], b12 = bp[2],  a11 = -bp[4],  a12 = -bp[5];
    const float b20 = bp[6], b21 = bp[7], b22 = bp[8],  a21 = -bp[10], a22 = -bp[11];
    const float b30 = lp[0], b31 = lp[1], b32 = lp[2],  a31 = -lp[4],  a32 = -lp[5];
    const float b40 = lp[6], b41 = lp[7], b42 = lp[8],  a41 = -lp[10], a42 = -lp[11];

    const int t_out0 = chunk * CHUNK;
    const int warm   = (t_out0 < WARM) ? t_out0 : WARM;  // 0 (chunk 0) or 64, block-uniform
    const int t0     = t_out0 - warm;

    // DF2T state: 2 per section
    float s11 = 0.f, s12 = 0.f;
    float s21 = 0.f, s22 = 0.f;
    float s31 = 0.f, s32 = 0.f;
    float s41 = 0.f, s42 = 0.f;

    const float* __restrict__ lq = x   + ((size_t)b * T_LEN + t0)     * C_LEN + c;
    float*       __restrict__ po = out + ((size_t)b * T_LEN + t_out0) * C_LEN + c;

    auto step = [&](float xn) -> float {
        // section 1 (bandpass)
        float y1 = fmaf(b10, xn, s11);
        s11 = fmaf(b11, xn, fmaf(a11, y1, s12));
        s12 = fmaf(b12, xn, a12 * y1);
        // section 2 (bandpass)
        float y2 = fmaf(b20, y1, s21);
        s21 = fmaf(b21, y1, fmaf(a21, y2, s22));
        s22 = fmaf(b22, y1, a22 * y2);
        // squaring nonlinearity
        float v = y2 * y2;
        // section 3 (lowpass)
        float y3 = fmaf(b30, v, s31);
        s31 = fmaf(b31, v, fmaf(a31, y3, s32));
        s32 = fmaf(b32, v, a32 * y3);
        // section 4 (lowpass)
        float y4 = fmaf(b40, y3, s41);
        s41 = fmaf(b41, y3, fmaf(a41, y4, s42));
        s42 = fmaf(b42, y3, a42 * y4);
        return y4;
    };

    // 4x8 register pipeline. All indices compile-time after unroll (no scratch).
    float P0[8], P1[8], P2[8], P3[8];

    auto load8 = [&](float* d) {
#pragma unroll
        for (int j = 0; j < 8; ++j) d[j] = lq[j * C_LEN];  // dword + imm offsets off one addr
        lq += 8 * C_LEN;
    };
    auto warm8 = [&](const float* d) {
#pragma unroll
        for (int j = 0; j < 8; ++j) step(d[j]);            // discard outputs
    };
    auto emit8 = [&](const float* d) {
#pragma unroll
        for (int j = 0; j < 8; ++j) {
            float y = step(d[j]);
            __builtin_nontemporal_store(y, po);            // streaming store, never re-read
            po += C_LEN;
        }
    };
    auto fence = [&]() { __builtin_amdgcn_sched_barrier(0); };

    // Prologue: 32 samples in flight before the first dependent FMA.
    load8(P0); load8(P1); load8(P2); load8(P3);
    fence();

    // Warm phase: warm/32 rotations (0 or 2). Each phase = {consume 8, reload 8},
    // fenced so the reload can't sink into a later region.
    const int nrot = warm >> 5;
    for (int r = 0; r < nrot; ++r) {
        warm8(P0); load8(P0); fence();
        warm8(P1); load8(P1); fence();
        warm8(P2); load8(P2); fence();
        warm8(P3); load8(P3); fence();
    }
    // Emit part 1: process [warm, warm+32), load [warm+32, warm+64). Last load ends
    // exactly at t0+warm+64 = t_out0+64 <= T: no OOB, no clamp needed.
    emit8(P0); load8(P0); fence();
    emit8(P1); load8(P1); fence();
    emit8(P2); load8(P2); fence();
    emit8(P3); load8(P3); fence();
    // Emit part 2: process [warm+32, warm+64), no further loads.
    emit8(P0); fence();
    emit8(P1); fence();
    emit8(P2); fence();
    emit8(P3);
}

extern "C" void kernel_launch(void* const* d_in, const int* in_sizes, int n_in,
                              void* d_out, int out_size, void* d_ws, size_t ws_size,
                              hipStream_t stream) {
    const float* x  = (const float*)d_in[0];
    const float* bp = (const float*)d_in[1];
    const float* lp = (const float*)d_in[2];
    float* out      = (float*)d_out;

    dim3 grid(T_LEN / CHUNK, B_LEN / 4);   // 256 x 4 = 1024 blocks -> 4 blocks/CU, 16 waves/CU
    dim3 block(256);                        // 4 waves: 4 batches x 64 channels
    iir_pipe_kernel<<<grid, block, 0, stream>>>(x, bp, lp, out);
}

// Round 3
// 117.239 us; speedup vs baseline: 1.0187x; 1.0187x over previous
//
#include <hip/hip_runtime.h>

// x: [B=16, T=16384, C=64] fp32. bp_sos/lp_sos: [2,6] fp32 rows (b0,b1,b2,a0,a1,a2; a0==1).
#define B_LEN 16
#define T_LEN 16384
#define C_LEN 64
#define CHUNK 128   // R8: 64->128. warm amp 2.0x -> 1.5x (VALU floor 9.6us -> 7.2us).
#define WARM  64    // zero-state warmup; transient ~0.83^64 ~ 7e-6 (empirically safe: absmax 0.0156)

// R8 theory: R7 (fences + launch_bounds min-waves) got kernel ~51 -> ~35us (VGPR
// pipeline materialized; kernel dropped below the 42us fills in top-5). Remaining
// gap to the 21.3us memory floor ~= the VALU component (9.6us at 2x warm amp) +
// phase bubbles. This round cuts the amp: CHUNK=128 (warm 64 per 128 outputs).
// Occupancy drops 16 -> 8 waves/CU, but latency hiding here is ILP (32-sample
// prefetch ring, ~2200 issue-cycles of distance), not TLP.
// Pipeline depth stays 4x8: deeper would push outstanding vmcnt ops past the
// 6-bit 63 limit (5 phases x (8 loads + 8 stores) = 80) and force over-strict
// waits on store-acks.
// Stores: batched per-phase with immediate offsets (1 addr bump / 8 stores).
// step() arithmetic order unchanged; second half of each chunk gets warm>=128 so
// absmax can only stay or shrink vs 0.015625.
__global__ __launch_bounds__(256, 2) void iir_pipe_kernel(
    const float* __restrict__ x,
    const float* __restrict__ bp,
    const float* __restrict__ lp,
    float* __restrict__ out)
{
    const int c     = threadIdx.x & 63;        // channel within batch
    const int bsub  = threadIdx.x >> 6;        // 0..3
    const int b     = blockIdx.y * 4 + bsub;   // batch 0..15
    const int chunk = blockIdx.x;              // 0..T/CHUNK-1

    // Uniform coefficients -> scalar (SGPR) loads. a's negated so updates are pure FMA.
    const float b10 = bp[0], b11 = bp[1], b12 = bp[2],  a11 = -bp[4],  a12 = -bp[5];
    const float b20 = bp[6], b21 = bp[7], b22 = bp[8],  a21 = -bp[10], a22 = -bp[11];
    const float b30 = lp[0], b31 = lp[1], b32 = lp[2],  a31 = -lp[4],  a32 = -lp[5];
    const float b40 = lp[6], b41 = lp[7], b42 = lp[8],  a41 = -lp[10], a42 = -lp[11];

    const int t_out0 = chunk * CHUNK;
    const int warm   = (t_out0 < WARM) ? t_out0 : WARM;  // 0 (chunk 0) or 64, block-uniform
    const int t0     = t_out0 - warm;

    // DF2T state: 2 per section
    float s11 = 0.f, s12 = 0.f;
    float s21 = 0.f, s22 = 0.f;
    float s31 = 0.f, s32 = 0.f;
    float s41 = 0.f, s42 = 0.f;

    const float* __restrict__ lq = x   + ((size_t)b * T_LEN + t0)     * C_LEN + c;
    float*       __restrict__ po = out + ((size_t)b * T_LEN + t_out0) * C_LEN + c;

    auto step = [&](float xn) -> float {
        // section 1 (bandpass)
        float y1 = fmaf(b10, xn, s11);
        s11 = fmaf(b11, xn, fmaf(a11, y1, s12));
        s12 = fmaf(b12, xn, a12 * y1);
        // section 2 (bandpass)
        float y2 = fmaf(b20, y1, s21);
        s21 = fmaf(b21, y1, fmaf(a21, y2, s22));
        s22 = fmaf(b22, y1, a22 * y2);
        // squaring nonlinearity
        float v = y2 * y2;
        // section 3 (lowpass)
        float y3 = fmaf(b30, v, s31);
        s31 = fmaf(b31, v, fmaf(a31, y3, s32));
        s32 = fmaf(b32, v, a32 * y3);
        // section 4 (lowpass)
        float y4 = fmaf(b40, y3, s41);
        s41 = fmaf(b41, y3, fmaf(a41, y4, s42));
        s42 = fmaf(b42, y3, a42 * y4);
        return y4;
    };

    // 4x8 register pipeline. All indices compile-time after unroll (no scratch).
    float P0[8], P1[8], P2[8], P3[8];

    auto load8 = [&](float* d) {
#pragma unroll
        for (int j = 0; j < 8; ++j) d[j] = lq[j * C_LEN];  // dword + imm offsets off one addr
        lq += 8 * C_LEN;
    };
    auto warm8 = [&](const float* d) {
#pragma unroll
        for (int j = 0; j < 8; ++j) step(d[j]);            // discard outputs
    };
    auto emit8 = [&](const float* d) {
        float y[8];
#pragma unroll
        for (int j = 0; j < 8; ++j) y[j] = step(d[j]);
#pragma unroll
        for (int j = 0; j < 8; ++j)
            __builtin_nontemporal_store(y[j], po + j * C_LEN);  // imm offsets, 1 bump/phase
        po += 8 * C_LEN;
    };
    auto fence = [&]() { __builtin_amdgcn_sched_barrier(0); };

    // Prologue: 32 samples in flight before the first dependent FMA.
    load8(P0); load8(P1); load8(P2); load8(P3);
    fence();

    // Warm phase: warm/32 rotations (0 or 2). Each phase = {consume 8, reload 8},
    // fenced so the reload can't sink into a later region.
    const int nrot = warm >> 5;
    for (int r = 0; r < nrot; ++r) {
        warm8(P0); load8(P0); fence();
        warm8(P1); load8(P1); fence();
        warm8(P2); load8(P2); fence();
        warm8(P3); load8(P3); fence();
    }
    // Emit with reload: (CHUNK-32)/32 = 3 rotations. Consume [warm+r*32, warm+(r+1)*32),
    // load [warm+(r+1)*32, warm+(r+2)*32). Total loads = warm + CHUNK, ending exactly
    // at t_out0 + CHUNK <= T: no OOB.
#pragma unroll 1
    for (int r = 0; r < (CHUNK - 32) / 32; ++r) {
        emit8(P0); load8(P0); fence();
        emit8(P1); load8(P1); fence();
        emit8(P2); load8(P2); fence();
        emit8(P3); load8(P3); fence();
    }
    // Final 32 samples: no further loads.
    emit8(P0); fence();
    emit8(P1); fence();
    emit8(P2); fence();
    emit8(P3);
}

extern "C" void kernel_launch(void* const* d_in, const int* in_sizes, int n_in,
                              void* d_out, int out_size, void* d_ws, size_t ws_size,
                              hipStream_t stream) {
    const float* x  = (const float*)d_in[0];
    const float* bp = (const float*)d_in[1];
    const float* lp = (const float*)d_in[2];
    float* out      = (float*)d_out;

    dim3 grid(T_LEN / CHUNK, B_LEN / 4);   // 128 x 4 = 512 blocks -> 2 blocks/CU, 8 waves/CU
    dim3 block(256);                        // 4 waves: 4 batches x 64 channels
    iir_pipe_kernel<<<grid, block, 0, stream>>>(x, bp, lp, out);
}

// Round 4
// 116.104 us; speedup vs baseline: 1.0286x; 1.0098x over previous
//
#include <hip/hip_runtime.h>

// x: [B=16, T=16384, C=64] fp32. bp_sos/lp_sos: [2,6] fp32 rows (b0,b1,b2,a0,a1,a2; a0==1).
#define B_LEN 16
#define T_LEN 16384
#define C_LEN 64
#define CHUNK 128   // warm amp 1.5x (R8)
#define WARM  64    // zero-state warmup; transient ~0.83^64 ~ 7e-6 (empirically safe: absmax 0.0156)

// R9: store-gating fix. R8 landed ~32us vs 21.3us memory floor; effective BW
// 4.2 TB/s vs 6.3 achievable (fills hit 6.3 in the same run). Theory: vmcnt
// decrements IN ISSUE ORDER, and R8's emit phases issue [8 stores][8 loads] --
// so the counted wait for group k's loads must drain 3 phases of older
// nontemporal stores first. Store-ack latency (write queue to HBM) serializes
// the read stream behind the write stream per wave.
// Fix: emit phase order = [compute y][prefetch loads][stores], with a
// sched_barrier between loads and stores. Loads now sit ahead of same-phase
// stores in the vmcnt FIFO; their wait no longer inherits store drain time.
// Anti-dep (loads overwrite Pk as compute reads it) resolves per-register:
// load Pk[j] issues as soon as step(d[j]) has consumed it.
// Arithmetic & load/store sets identical to R8 -> bit-identical output.
__global__ __launch_bounds__(256, 2) void iir_pipe_kernel(
    const float* __restrict__ x,
    const float* __restrict__ bp,
    const float* __restrict__ lp,
    float* __restrict__ out)
{
    const int c     = threadIdx.x & 63;        // channel within batch
    const int bsub  = threadIdx.x >> 6;        // 0..3
    const int b     = blockIdx.y * 4 + bsub;   // batch 0..15
    const int chunk = blockIdx.x;              // 0..T/CHUNK-1

    // Uniform coefficients -> scalar (SGPR) loads. a's negated so updates are pure FMA.
    const float b10 = bp[0], b11 = bp[1], b12 = bp[2],  a11 = -bp[4],  a12 = -bp[5];
    const float b20 = bp[6], b21 = bp[7], b22 = bp[8],  a21 = -bp[10], a22 = -bp[11];
    const float b30 = lp[0], b31 = lp[1], b32 = lp[2],  a31 = -lp[4],  a32 = -lp[5];
    const float b40 = lp[6], b41 = lp[7], b42 = lp[8],  a41 = -lp[10], a42 = -lp[11];

    const int t_out0 = chunk * CHUNK;
    const int warm   = (t_out0 < WARM) ? t_out0 : WARM;  // 0 (chunk 0) or 64, block-uniform
    const int t0     = t_out0 - warm;

    // DF2T state: 2 per section
    float s11 = 0.f, s12 = 0.f;
    float s21 = 0.f, s22 = 0.f;
    float s31 = 0.f, s32 = 0.f;
    float s41 = 0.f, s42 = 0.f;

    const float* __restrict__ lq = x   + ((size_t)b * T_LEN + t0)     * C_LEN + c;
    float*       __restrict__ po = out + ((size_t)b * T_LEN + t_out0) * C_LEN + c;

    auto step = [&](float xn) -> float {
        // section 1 (bandpass)
        float y1 = fmaf(b10, xn, s11);
        s11 = fmaf(b11, xn, fmaf(a11, y1, s12));
        s12 = fmaf(b12, xn, a12 * y1);
        // section 2 (bandpass)
        float y2 = fmaf(b20, y1, s21);
        s21 = fmaf(b21, y1, fmaf(a21, y2, s22));
        s22 = fmaf(b22, y1, a22 * y2);
        // squaring nonlinearity
        float v = y2 * y2;
        // section 3 (lowpass)
        float y3 = fmaf(b30, v, s31);
        s31 = fmaf(b31, v, fmaf(a31, y3, s32));
        s32 = fmaf(b32, v, a32 * y3);
        // section 4 (lowpass)
        float y4 = fmaf(b40, y3, s41);
        s41 = fmaf(b41, y3, fmaf(a41, y4, s42));
        s42 = fmaf(b42, y3, a42 * y4);
        return y4;
    };

    // 4x8 register pipeline. All indices compile-time after unroll (no scratch).
    float P0[8], P1[8], P2[8], P3[8];

    auto load8 = [&](float* d) {
#pragma unroll
        for (int j = 0; j < 8; ++j) d[j] = lq[j * C_LEN];  // dword + imm offsets off one addr
        lq += 8 * C_LEN;
    };
    auto warm8 = [&](const float* d) {
#pragma unroll
        for (int j = 0; j < 8; ++j) step(d[j]);            // discard outputs
    };
    auto fence = [&]() { __builtin_amdgcn_sched_barrier(0); };

    // Emit phase: compute -> prefetch loads -> stores (stores LAST in vmcnt FIFO).
    auto emit8_reload = [&](float* d) {
        float y[8];
#pragma unroll
        for (int j = 0; j < 8; ++j) y[j] = step(d[j]);
        load8(d);          // overwrites d; per-reg anti-dep lets load j trail step j
        fence();           // stores must not be scheduled above the loads
#pragma unroll
        for (int j = 0; j < 8; ++j)
            __builtin_nontemporal_store(y[j], po + j * C_LEN);
        po += 8 * C_LEN;
        fence();
    };
    auto emit8_final = [&](const float* d) {
        float y[8];
#pragma unroll
        for (int j = 0; j < 8; ++j) y[j] = step(d[j]);
#pragma unroll
        for (int j = 0; j < 8; ++j)
            __builtin_nontemporal_store(y[j], po + j * C_LEN);
        po += 8 * C_LEN;
        fence();
    };

    // Prologue: 32 samples in flight before the first dependent FMA.
    load8(P0); load8(P1); load8(P2); load8(P3);
    fence();

    // Warm phase: warm/32 rotations (0 or 2). {consume 8, reload 8}, fenced.
    const int nrot = warm >> 5;
    for (int r = 0; r < nrot; ++r) {
        warm8(P0); load8(P0); fence();
        warm8(P1); load8(P1); fence();
        warm8(P2); load8(P2); fence();
        warm8(P3); load8(P3); fence();
    }
    // Emit with reload: 3 rotations. Consume [warm+r*32, warm+(r+1)*32),
    // load [warm+(r+1)*32, warm+(r+2)*32). Total loads = warm + CHUNK, ending
    // exactly at t_out0 + CHUNK <= T: no OOB.
#pragma unroll 1
    for (int r = 0; r < (CHUNK - 32) / 32; ++r) {
        emit8_reload(P0);
        emit8_reload(P1);
        emit8_reload(P2);
        emit8_reload(P3);
    }
    // Final 32 samples: no further loads.
    emit8_final(P0);
    emit8_final(P1);
    emit8_final(P2);
    emit8_final(P3);
}

extern "C" void kernel_launch(void* const* d_in, const int* in_sizes, int n_in,
                              void* d_out, int out_size, void* d_ws, size_t ws_size,
                              hipStream_t stream) {
    const float* x  = (const float*)d_in[0];
    const float* bp = (const float*)d_in[1];
    const float* lp = (const float*)d_in[2];
    float* out      = (float*)d_out;

    dim3 grid(T_LEN / CHUNK, B_LEN / 4);   // 128 x 4 = 512 blocks -> 2 blocks/CU, 8 waves/CU
    dim3 block(256);                        // 4 waves: 4 batches x 64 channels
    iir_pipe_kernel<<<grid, block, 0, stream>>>(x, bp, lp, out);
}